// Round 28
// baseline (1715.713 us; speedup 1.0000x reference)
//
#include <hip/hip_runtime.h>
#include <hip/hip_bf16.h>

#define NLAT 511
#define NLON 512
#define LMAX 511
#define MMAX 257
#define WSP 513             // W_lds row stride (512 + 1 pad)
#define KT2 16              // kk2 rows per tile (= 8 original k)
#define A_PER_M 16352       // floats
#define P_PER_M 65536       // floats: 4 splits * 512 l * 32 j

typedef unsigned short u16;
typedef unsigned int u32;

__device__ __forceinline__ u16 f2bf(float a) {
    __hip_bfloat16 h = __float2bfloat16(a);
    return *reinterpret_cast<u16*>(&h);
}

// ---------------------------------------------------------------------------
// Kernel 1: radix-2 LDS FFT per (ring, comp) — unchanged (verified).
// ---------------------------------------------------------------------------
__global__ __launch_bounds__(256) void fft3(const float* __restrict__ x,
                                            float* __restrict__ A,
                                            int m_lo, int m_hi) {
    const int kb   = blockIdx.x;
    const int klat = kb >> 1;
    const int c    = kb & 1;
    const int t    = threadIdx.x;

    __shared__ __align__(16) float re[8][512];
    __shared__ __align__(16) float im[8][512];

    #pragma unroll
    for (int b = 0; b < 8; ++b) {
        const float* row = x + ((size_t)(b * 2 + c) * NLAT + klat) * NLON;
        #pragma unroll
        for (int h = 0; h < 2; ++h) {
            int n  = h * 256 + t;
            int rn = (int)(__brev((u32)n) >> 23);
            re[b][rn] = row[n];
            im[b][rn] = 0.0f;
        }
    }
    __syncthreads();

    for (int s = 1; s <= 9; ++s) {
        const int half = 1 << (s - 1);
        const int j    = t & (half - 1);
        const int p0   = ((t >> (s - 1)) << s) + j;
        const int p1   = p0 + half;
        float sn, cs;
        sincosf(-6.28318530717958647692f * (float)j / (float)(1 << s), &sn, &cs);
        #pragma unroll
        for (int b = 0; b < 8; ++b) {
            float ar = re[b][p0], ai = im[b][p0];
            float br = re[b][p1], bi = im[b][p1];
            float tr = fmaf(br, cs, -bi * sn);
            float ti = fmaf(br, sn,  bi * cs);
            re[b][p0] = ar + tr;  im[b][p0] = ai + ti;
            re[b][p1] = ar - tr;  im[b][p1] = ai - ti;
        }
        __syncthreads();
    }

    for (int m = m_lo + t; m < m_hi; m += 256) {
        float4* d4 = (float4*)(A + ((size_t)(m - m_lo) * NLAT + klat) * 32 + c * 16);
        d4[0] = make_float4(re[0][m], re[1][m], re[2][m], re[3][m]);
        d4[1] = make_float4(re[4][m], re[5][m], re[6][m], re[7][m]);
        d4[2] = make_float4(im[0][m], im[1][m], im[2][m], im[3][m]);
        d4[3] = make_float4(im[4][m], im[5][m], im[6][m], im[7][m]);
    }
}

// ---------------------------------------------------------------------------
// Kernel 2: leg13 — GEMM-anatomy Legendre.  Block = (m, k-quarter).
// OUT[512 l][32 j] += sum_kk2 W~[kk2][l] * B~[kk2][j], kk2 = 2k+d stacking
// (wA,wB); B~ = sign/permuted A columns (verified UPD algebra).
// Thread tile 8 l (stride 64) x 8 j = 64 acc.  LDS 34.9 KB -> 4 blocks/CU.
// Partials (f32) to P; reduced by red13.
// ---------------------------------------------------------------------------
__global__ __launch_bounds__(256, 4) void leg13(const float* __restrict__ A,
                                                const float* __restrict__ w,
                                                float* __restrict__ P,
                                                int m_lo) {
    const int ks = blockIdx.x & 3;            // k-quarter 0..3
    const int mi = blockIdx.x >> 2;
    const int m  = m_lo + mi;
    const int t  = threadIdx.x;

    __shared__ float Wl[KT2 * WSP];           // 32,832 B
    __shared__ float Bl[KT2 * 32];            //  2,048 B

    const float* __restrict__ Am = A + (size_t)mi * A_PER_M;
    const size_t wplane = (size_t)MMAX * LMAX * NLAT;
    const float* __restrict__ wm = w + (size_t)m * LMAX * NLAT;

    const int tl = t >> 2;                    // l = tl + 64*i
    const int j0 = (t & 3) * 8;

    float acc[8][8];
    #pragma unroll
    for (int i = 0; i < 8; ++i)
        #pragma unroll
        for (int jj = 0; jj < 8; ++jj) acc[i][jj] = 0.0f;

    const int k0blk = ks * 128;

    for (int kt = 0; kt < 16; ++kt) {
        const int k0 = k0blk + kt * 8;        // 8 original k this tile
        __syncthreads();                      // previous tile's compute done

        // ---- stage W~: u = it*256+t: d=u>>11, lq=(u>>2)&511, kq=u&3 ----
        #pragma unroll
        for (int it = 0; it < 16; ++it) {
            const int u  = it * 256 + t;
            const int d  = u >> 11;
            const int lq = (u >> 2) & 511;
            const int kq = u & 3;
            const int lw = (lq < LMAX) ? lq : (LMAX - 1);   // l=511 discarded
            const int kg = k0 + 2 * kq;
            const size_t rowb = (size_t)d * wplane + (size_t)lw * NLAT;
            float2 v;
            if (kg + 1 <= 510)      v = *(const float2*)(wm + rowb + kg);
            else if (kg <= 510)     { v.x = wm[rowb + kg]; v.y = 0.0f; }
            else                    { v.x = 0.0f; v.y = 0.0f; }
            Wl[(4 * kq + d) * WSP + lq]     = v.x;   // kk2 = 2*(2kq)   + d
            Wl[(4 * kq + 2 + d) * WSP + lq] = v.y;   // kk2 = 2*(2kq+1) + d
        }

        // ---- stage B~: kloc = t>>5 (0..7), j = t&31 ----
        {
            const int kloc = t >> 5, j = t & 31;
            const int kg = k0 + kloc;
            const int grp = j >> 3, b = j & 7;
            const int s0 = (grp == 0) ? b : (grp == 1) ? 8 + b
                         : (grp == 2) ? 16 + b : 24 + b;
            const int s1 = (grp == 0) ? 24 + b : (grp == 1) ? 16 + b
                         : (grp == 2) ? 8 + b : b;
            const float g0 = (grp < 2) ? 1.0f : -1.0f;
            const float g1 = (grp == 1 || grp == 3) ? 1.0f : -1.0f;
            float a0 = 0.0f, a1 = 0.0f;
            if (kg <= 510) {
                a0 = g0 * Am[(size_t)kg * 32 + s0];
                a1 = g1 * Am[(size_t)kg * 32 + s1];
            }
            Bl[(2 * kloc) * 32 + j]     = a0;
            Bl[(2 * kloc + 1) * 32 + j] = a1;
        }
        __syncthreads();

        // ---- compute: 16 kk2 x (8 W reads + 8 B reads + 64 FMA) ----
        #pragma unroll
        for (int kk = 0; kk < KT2; ++kk) {
            float wv[8], bv[8];
            #pragma unroll
            for (int i = 0; i < 8; ++i) wv[i] = Wl[kk * WSP + tl + 64 * i];
            {
                const float4 b0 = *(const float4*)&Bl[kk * 32 + j0];
                const float4 b1 = *(const float4*)&Bl[kk * 32 + j0 + 4];
                bv[0] = b0.x; bv[1] = b0.y; bv[2] = b0.z; bv[3] = b0.w;
                bv[4] = b1.x; bv[5] = b1.y; bv[6] = b1.z; bv[7] = b1.w;
            }
            #pragma unroll
            for (int i = 0; i < 8; ++i)
                #pragma unroll
                for (int jj = 0; jj < 8; ++jj)
                    acc[i][jj] = fmaf(wv[i], bv[jj], acc[i][jj]);
        }
    }

    // ---- store partials: P[(mi*4+ks)*512 + l][32] ----
    float* Pb = P + (size_t)(mi * 4 + ks) * 512 * 32;
    #pragma unroll
    for (int i = 0; i < 8; ++i) {
        const int l = tl + 64 * i;
        float4* dst = (float4*)&Pb[(size_t)l * 32 + j0];
        dst[0] = make_float4(acc[i][0], acc[i][1], acc[i][2], acc[i][3]);
        dst[1] = make_float4(acc[i][4], acc[i][5], acc[i][6], acc[i][7]);
    }
}

// ---------------------------------------------------------------------------
// Kernel 3: red13 — sum the 4 k-quarter partials, bf16 +1-shift store.
// Block = (mi, l-block of 8); thread = (l-offset, j).
// ---------------------------------------------------------------------------
__global__ __launch_bounds__(256) void red13(const float* __restrict__ P,
                                             u16* __restrict__ out,
                                             int m_lo) {
    const int lblk = blockIdx.x & 63;
    const int mi   = blockIdx.x >> 6;
    const int m    = m_lo + mi;
    const int t    = threadIdx.x;
    const int l    = lblk * 8 + (t >> 5);
    const int j    = t & 31;
    if (l >= LMAX) return;

    const size_t base = (size_t)mi * 4 * 512 * 32 + (size_t)l * 32 + j;
    float v = 0.0f;
    #pragma unroll
    for (int s = 0; s < 4; ++s) v += P[base + (size_t)s * 512 * 32];

    const int cout = j >> 4, ri = (j >> 3) & 1, b = j & 7;
    const size_t cidx = ((size_t)(b * 2 + cout) * LMAX + l) * MMAX + m;
    // +1 SHIFT (measured R14-R17): validated flat[jj] = our u16[jj+1].
    out[2 * cidx + 1 + ri] = f2bf(v);
}

extern "C" void kernel_launch(void* const* d_in, const int* in_sizes, int n_in,
                              void* d_out, int out_size, void* d_ws, size_t ws_size,
                              hipStream_t stream) {
    const float* x = (const float*)d_in[0];   // [8][2][511][512] f32
    const float* w = (const float*)d_in[1];   // [2][257][511][511] f32
    u16* out = (u16*)d_out;                   // bf16, validated at +2 B
    float* ws = (float*)d_ws;

    const size_t per_m = (size_t)(A_PER_M + P_PER_M) * sizeof(float); // 327,552 B
    int mchunk = (int)(ws_size / per_m);
    if (mchunk > MMAX) mchunk = MMAX;
    if (mchunk < 1) mchunk = 1;

    float* A = ws;
    float* P = ws + (size_t)mchunk * A_PER_M;

    for (int m0 = 0; m0 < MMAX; m0 += mchunk) {
        int m1 = m0 + mchunk;
        if (m1 > MMAX) m1 = MMAX;
        const int mc = m1 - m0;
        fft3<<<NLAT * 2, 256, 0, stream>>>(x, A, m0, m1);
        leg13<<<mc * 4, 256, 0, stream>>>(A, w, P, m0);
        red13<<<mc * 64, 256, 0, stream>>>(P, out, m0);
    }
}

// Round 29
// 877.710 us; speedup vs baseline: 1.9548x; 1.9548x over previous
//
#include <hip/hip_runtime.h>
#include <hip/hip_bf16.h>

#define NLAT 511
#define NLON 512
#define LMAX 511
#define MMAX 257
#define PAD 34              // As row stride: b64-aligned, 2-way banks (free)

typedef unsigned short u16;
typedef unsigned int u32;

__device__ __forceinline__ u16 f2bf(float a) {
    __hip_bfloat16 h = __float2bfloat16(a);
    return *reinterpret_cast<u16*>(&h);
}

// A layout (f32, in d_ws): A[mi][k][j], j = c*16 + ri*8 + b.  Per-m: 65,408 B.

// ---------------------------------------------------------------------------
// Kernel 1: radix-2 LDS FFT per (ring, comp) — unchanged (verified).
// ---------------------------------------------------------------------------
__global__ __launch_bounds__(256) void fft3(const float* __restrict__ x,
                                            float* __restrict__ A,
                                            int m_lo, int m_hi) {
    const int kb   = blockIdx.x;
    const int klat = kb >> 1;
    const int c    = kb & 1;
    const int t    = threadIdx.x;

    __shared__ __align__(16) float re[8][512];
    __shared__ __align__(16) float im[8][512];

    #pragma unroll
    for (int b = 0; b < 8; ++b) {
        const float* row = x + ((size_t)(b * 2 + c) * NLAT + klat) * NLON;
        #pragma unroll
        for (int h = 0; h < 2; ++h) {
            int n  = h * 256 + t;
            int rn = (int)(__brev((u32)n) >> 23);
            re[b][rn] = row[n];
            im[b][rn] = 0.0f;
        }
    }
    __syncthreads();

    for (int s = 1; s <= 9; ++s) {
        const int half = 1 << (s - 1);
        const int j    = t & (half - 1);
        const int p0   = ((t >> (s - 1)) << s) + j;
        const int p1   = p0 + half;
        float sn, cs;
        sincosf(-6.28318530717958647692f * (float)j / (float)(1 << s), &sn, &cs);
        #pragma unroll
        for (int b = 0; b < 8; ++b) {
            float ar = re[b][p0], ai = im[b][p0];
            float br = re[b][p1], bi = im[b][p1];
            float tr = fmaf(br, cs, -bi * sn);
            float ti = fmaf(br, sn,  bi * cs);
            re[b][p0] = ar + tr;  im[b][p0] = ai + ti;
            re[b][p1] = ar - tr;  im[b][p1] = ai - ti;
        }
        __syncthreads();
    }

    for (int m = m_lo + t; m < m_hi; m += 256) {
        float4* d4 = (float4*)(A + ((size_t)(m - m_lo) * NLAT + klat) * 32 + c * 16);
        d4[0] = make_float4(re[0][m], re[1][m], re[2][m], re[3][m]);
        d4[1] = make_float4(re[4][m], re[5][m], re[6][m], re[7][m]);
        d4[2] = make_float4(im[0][m], im[1][m], im[2][m], im[3][m]);
        d4[3] = make_float4(im[4][m], im[5][m], im[6][m], im[7][m]);
    }
}

// ---------------------------------------------------------------------------
// Kernel 2: leg14 — leg11's verified math with the latency structure fixed:
//  * 2 l per wave (acc 64 regs), launch_bounds(256,4) -> <=128 VGPR target
//    -> 4 waves/SIMD (16 waves/CU).
//  * As staged in HALVES (256 k, 34,816 B -> 4 blocks/CU); k=511 row zeroed.
//  * All 16 w-loads of a half issued as one batch BEFORE the As staging;
//    no per-load selects (out-of-range k killed by the zero A-row).
// ---------------------------------------------------------------------------
__global__ __launch_bounds__(256, 4) void leg14(const float* __restrict__ A,
                                                const float* __restrict__ w,
                                                u16* __restrict__ out,
                                                int m_lo) {
    const int lg   = blockIdx.x & 63;          // l-group 0..63 (8 l each)
    const int mi   = blockIdx.x >> 6;
    const int m    = m_lo + mi;
    const int t    = threadIdx.x;
    const int wid  = t >> 6;                   // wave 0..3
    const int lane = t & 63;

    __shared__ float As[256 * PAD];            // 34,816 B -> 4 blocks/CU

    // this wave's 2 l rows (l0 <= 510 always; l1 may be 511 -> clamped, discarded)
    const int l0  = lg * 8 + wid * 2;
    const int l1  = l0 + 1;
    const int l1c = (l1 < LMAX) ? l1 : (LMAX - 1);
    const size_t wpl = (size_t)MMAX * LMAX * NLAT;
    const float* __restrict__ w0r0 = w + ((size_t)m * LMAX + l0) * NLAT;
    const float* __restrict__ w0r1 = w + ((size_t)m * LMAX + l1c) * NLAT;

    const float* __restrict__ Amg = A + (size_t)mi * (NLAT * 32);

    float acc0[32], acc1[32];
    #pragma unroll
    for (int j = 0; j < 32; ++j) { acc0[j] = 0.0f; acc1[j] = 0.0f; }

    for (int h = 0; h < 2; ++h) {
        // ---- 1. batch-issue ALL 16 w loads for this half (no selects) ----
        float wa0[4], wb0[4], wa1[4], wb1[4];
        #pragma unroll
        for (int tt = 0; tt < 4; ++tt) {
            const int myk = h * 256 + tt * 64 + lane;
            const int kc  = (myk < NLAT) ? myk : (NLAT - 1);   // clamp; k=511
            wa0[tt] = w0r0[kc];              //   contribution killed by zero
            wb0[tt] = w0r0[wpl + kc];        //   A-row, so raw loads are safe
            wa1[tt] = w0r1[kc];
            wb1[tt] = w0r1[wpl + kc];
        }

        // ---- 2. stage As half (k = h*256 .. h*256+255; row 255 of h=1 = 0) ----
        {
            const float2* src = (const float2*)(Amg + (size_t)(h * 256) * 32);
            #pragma unroll
            for (int it = 0; it < 16; ++it) {
                const int i  = it * 256 + t;
                const int kr = i >> 4, p = i & 15;
                float2 v;
                if (h == 1 && kr == 255) v = make_float2(0.0f, 0.0f);
                else                     v = src[(size_t)kr * 16 + p];
                *(float2*)&As[kr * PAD + 2 * p] = v;
            }
        }
        __syncthreads();

        // ---- 3. compute 4 tiles ----
        #pragma unroll
        for (int tt = 0; tt < 4; ++tt) {
            const int krow = tt * 64 + lane;   // As row 0..255
            float Ak[32];
            {
                const float* base = &As[krow * PAD];
                #pragma unroll
                for (int p = 0; p < 16; ++p) {   // ds_read_b64, 2-way banks
                    const float2 v = *(const float2*)&base[2 * p];
                    Ak[2 * p]     = v.x;
                    Ak[2 * p + 1] = v.y;
                }
            }
#define ACCUM(ACC, WA, WB)                                                  \
            _Pragma("unroll")                                               \
            for (int b = 0; b < 8; ++b) {                                   \
                ACC[b]      = fmaf(WA, Ak[b],      fmaf(-WB, Ak[24 + b], ACC[b]));      \
                ACC[8 + b]  = fmaf(WA, Ak[8 + b],  fmaf( WB, Ak[16 + b], ACC[8 + b]));  \
                ACC[16 + b] = fmaf(-WB, Ak[8 + b], fmaf(-WA, Ak[16 + b], ACC[16 + b])); \
                ACC[24 + b] = fmaf(WB, Ak[b],      fmaf(-WA, Ak[24 + b], ACC[24 + b])); \
            }
            ACCUM(acc0, wa0[tt], wb0[tt])
            ACCUM(acc1, wa1[tt], wb1[tt])
#undef ACCUM
        }
        __syncthreads();                       // before next half restage
    }

    // ---- per-l reduce via LDS transpose (reuse As); no pointers to accs ----
    float* red = As + wid * (64 * PAD);        // 4 waves x 8,704 B = 34,816 B
    const int o = lane & 31;
    const int hh = lane >> 5;

#define REDSTEP(ACC, LI)                                                    \
    {                                                                       \
        __syncthreads();                                                    \
        _Pragma("unroll")                                                   \
        for (int p = 0; p < 16; ++p)                                        \
            *(float2*)&red[lane * PAD + 2 * p] =                            \
                make_float2(ACC[2 * p], ACC[2 * p + 1]);                    \
        __syncthreads();                                                    \
        float s = 0.0f;                                                     \
        _Pragma("unroll")                                                   \
        for (int i = 0; i < 32; ++i)                                        \
            s += red[(32 * hh + i) * PAD + o];                              \
        s += __shfl_xor(s, 32, 64);                                         \
        const int l = l0 + (LI);                                            \
        if (lane < 32 && l < LMAX) {                                        \
            const int cout = o >> 4, ri = (o >> 3) & 1, b = o & 7;          \
            const size_t cidx =                                             \
                ((size_t)(b * 2 + cout) * LMAX + l) * MMAX + m;             \
            /* +1 SHIFT (measured R14-R17): flat[j] = our u16[j+1]. */      \
            out[2 * cidx + 1 + ri] = f2bf(s);                               \
        }                                                                   \
    }

    REDSTEP(acc0, 0)
    REDSTEP(acc1, 1)
#undef REDSTEP
}

extern "C" void kernel_launch(void* const* d_in, const int* in_sizes, int n_in,
                              void* d_out, int out_size, void* d_ws, size_t ws_size,
                              hipStream_t stream) {
    const float* x = (const float*)d_in[0];   // [8][2][511][512] f32
    const float* w = (const float*)d_in[1];   // [2][257][511][511] f32
    u16* out = (u16*)d_out;                   // bf16, validated at +2 B
    float* A = (float*)d_ws;

    const size_t per_m = (size_t)NLAT * 32 * sizeof(float);   // 65,408 B
    int mchunk = (int)(ws_size / per_m);
    if (mchunk > MMAX) mchunk = MMAX;
    if (mchunk < 1) mchunk = 1;

    for (int m0 = 0; m0 < MMAX; m0 += mchunk) {
        int m1 = m0 + mchunk;
        if (m1 > MMAX) m1 = MMAX;
        const int mc = m1 - m0;
        fft3<<<NLAT * 2, 256, 0, stream>>>(x, A, m0, m1);
        leg14<<<mc * 64, 256, 0, stream>>>(A, w, out, m0);
    }
}

// Round 30
// 300.378 us; speedup vs baseline: 5.7119x; 2.9220x over previous
//
#include <hip/hip_runtime.h>
#include <hip/hip_bf16.h>

#define NLAT 511
#define NLON 512
#define LMAX 511
#define MMAX 257
#define PADW 520            // u16 row stride (512 data + 8 pad); rows 16B-aligned

typedef unsigned short u16;
typedef unsigned int u32;
typedef __attribute__((ext_vector_type(8))) short short8;
typedef __attribute__((ext_vector_type(4))) float f32x4;

__device__ __forceinline__ u16 f2bf(float a) {
    __hip_bfloat16 h = __float2bfloat16(a);
    return *reinterpret_cast<u16*>(&h);
}

// A layout (f32, in d_ws): A[mi][k][j], j = c*16 + ri*8 + b.  Per-m: 65,408 B.

// ---------------------------------------------------------------------------
// Kernel 1: radix-2 LDS FFT per (ring, comp) — unchanged (verified).
// ---------------------------------------------------------------------------
__global__ __launch_bounds__(256) void fft3(const float* __restrict__ x,
                                            float* __restrict__ A,
                                            int m_lo, int m_hi) {
    const int kb   = blockIdx.x;
    const int klat = kb >> 1;
    const int c    = kb & 1;
    const int t    = threadIdx.x;

    __shared__ __align__(16) float re[8][512];
    __shared__ __align__(16) float im[8][512];

    #pragma unroll
    for (int b = 0; b < 8; ++b) {
        const float* row = x + ((size_t)(b * 2 + c) * NLAT + klat) * NLON;
        #pragma unroll
        for (int h = 0; h < 2; ++h) {
            int n  = h * 256 + t;
            int rn = (int)(__brev((u32)n) >> 23);
            re[b][rn] = row[n];
            im[b][rn] = 0.0f;
        }
    }
    __syncthreads();

    for (int s = 1; s <= 9; ++s) {
        const int half = 1 << (s - 1);
        const int j    = t & (half - 1);
        const int p0   = ((t >> (s - 1)) << s) + j;
        const int p1   = p0 + half;
        float sn, cs;
        sincosf(-6.28318530717958647692f * (float)j / (float)(1 << s), &sn, &cs);
        #pragma unroll
        for (int b = 0; b < 8; ++b) {
            float ar = re[b][p0], ai = im[b][p0];
            float br = re[b][p1], bi = im[b][p1];
            float tr = fmaf(br, cs, -bi * sn);
            float ti = fmaf(br, sn,  bi * cs);
            re[b][p0] = ar + tr;  im[b][p0] = ai + ti;
            re[b][p1] = ar - tr;  im[b][p1] = ai - ti;
        }
        __syncthreads();
    }

    for (int m = m_lo + t; m < m_hi; m += 256) {
        float4* d4 = (float4*)(A + ((size_t)(m - m_lo) * NLAT + klat) * 32 + c * 16);
        d4[0] = make_float4(re[0][m], re[1][m], re[2][m], re[3][m]);
        d4[1] = make_float4(re[4][m], re[5][m], re[6][m], re[7][m]);
        d4[2] = make_float4(im[0][m], im[1][m], im[2][m], im[3][m]);
        d4[3] = make_float4(im[4][m], im[5][m], im[6][m], im[7][m]);
    }
}

// ---------------------------------------------------------------------------
// Kernel 2: legm — MFMA Legendre.  Block = (m, 64-l slab).  Per block:
//   OUT[64 x 32] = sum_d W_d[64 x 512] x B_d[512 x 32]   (bf16 in, f32 acc)
// 4 waves: wave (mt,jt) owns one 16x16 tile per 32-row chunk (2 chunks).
// B_d fragments live in registers (built from A via the verified UPD signs:
// d=0: B[k][n] = +-A[k][n]; d=1: the 24/8/-8/-24 permutation).  W chunks
// staged to LDS as bf16 [32][PADW], scalar f32 loads (rows 4B-aligned).
// k=511 pad zeroed in BOTH W and B.  k-map guess is self-cancelling (A and
// B share it); only lane&15 row/col map + verified C/D layout matter.
// ---------------------------------------------------------------------------
__global__ __launch_bounds__(256, 2) void legm(const float* __restrict__ A,
                                               const float* __restrict__ w,
                                               u16* __restrict__ out,
                                               int m_lo) {
    const int lq   = blockIdx.x & 7;          // 64-row slab 0..7
    const int mi   = blockIdx.x >> 3;
    const int m    = m_lo + mi;
    const int t    = threadIdx.x;
    const int wid  = t >> 6;
    const int lane = t & 63;

    __shared__ __align__(16) u16 Wl[32 * PADW];   // 33,280 B

    const float* __restrict__ Am = A + (size_t)mi * (NLAT * 32);
    const size_t wpl = (size_t)MMAX * LMAX * NLAT;

    const int mt  = wid & 1;                  // 16-row group within chunk
    const int jt  = wid >> 1;                 // 16-col group
    const int col = lane & 15;                // A-row / B-col / D-col
    const int kg  = lane >> 4;                // k-group 0..3
    const int n   = jt * 16 + col;            // output column 0..31

    f32x4 acc0 = {0.f, 0.f, 0.f, 0.f};
    f32x4 acc1 = {0.f, 0.f, 0.f, 0.f};

    const int sr = t >> 3;                    // staging LDS row 0..31
    const int sp = t & 7;                     // staging 64-elem part 0..7

    #pragma unroll
    for (int d = 0; d < 2; ++d) {
        // ---- build B_d fragments (registers) ----
        int src; float sg;
        if (d == 0) { src = n; sg = (n < 16) ? 1.f : -1.f; }
        else {
            if (n < 8)       { src = n + 24; sg = -1.f; }
            else if (n < 16) { src = n + 8;  sg =  1.f; }
            else if (n < 24) { src = n - 8;  sg = -1.f; }
            else             { src = n - 24; sg =  1.f; }
        }
        short8 bfr[16];
        #pragma unroll
        for (int ks = 0; ks < 16; ++ks) {
            short8 v;
            #pragma unroll
            for (int e = 0; e < 8; ++e) {
                const int k = ks * 32 + kg * 8 + e;
                const float x = (k <= 510) ? Am[(size_t)k * 32 + src] * sg : 0.f;
                v[e] = (short)f2bf(x);
            }
            bfr[ks] = v;
        }

        #pragma unroll
        for (int c = 0; c < 2; ++c) {
            __syncthreads();                  // prev phase LDS reads done

            // ---- stage W chunk: 32 rows x 511 k (f32 -> bf16 LDS) ----
            {
                const int row  = lq * 64 + c * 32 + sr;
                const int rowc = (row < LMAX) ? row : (LMAX - 1);
                const float* wr = w + (size_t)d * wpl
                                + ((size_t)m * LMAX + rowc) * NLAT + sp * 64;
                u32* dst = (u32*)&Wl[sr * PADW + sp * 64];
                #pragma unroll
                for (int j = 0; j < 16; ++j) {
                    float x0, x1, x2, x3;
                    if (sp == 7 && j == 15) {     // k = 508,509,510,(511->0)
                        x0 = wr[60]; x1 = wr[61]; x2 = wr[62]; x3 = 0.f;
                    } else {
                        x0 = wr[4 * j];     x1 = wr[4 * j + 1];
                        x2 = wr[4 * j + 2]; x3 = wr[4 * j + 3];
                    }
                    dst[2 * j]     = (u32)f2bf(x0) | ((u32)f2bf(x1) << 16);
                    dst[2 * j + 1] = (u32)f2bf(x2) | ((u32)f2bf(x3) << 16);
                }
            }
            __syncthreads();

            // ---- 16 MFMAs over K = 512 ----
            #pragma unroll
            for (int ks = 0; ks < 16; ++ks) {
                const short8 af = *(const short8*)((const char*)Wl
                    + (size_t)(mt * 16 + col) * (PADW * 2) + ks * 64 + kg * 16);
                if (c == 0)
                    acc0 = __builtin_amdgcn_mfma_f32_16x16x32_bf16(af, bfr[ks], acc0, 0, 0, 0);
                else
                    acc1 = __builtin_amdgcn_mfma_f32_16x16x32_bf16(af, bfr[ks], acc1, 0, 0, 0);
            }
        }
    }

    // ---- store: D col = lane&15 (= n), row = kg*4 + r  [verified m89] ----
    const int cout = n >> 4, ri = (n >> 3) & 1, b = n & 7;
    #pragma unroll
    for (int c = 0; c < 2; ++c) {
        #pragma unroll
        for (int r = 0; r < 4; ++r) {
            const int l = lq * 64 + c * 32 + mt * 16 + kg * 4 + r;
            if (l < LMAX) {
                const float v = (c == 0) ? acc0[r] : acc1[r];
                const size_t cidx = ((size_t)(b * 2 + cout) * LMAX + l) * MMAX + m;
                // +1 SHIFT (measured R14-R17): validated flat[j] = our u16[j+1].
                out[2 * cidx + 1 + ri] = f2bf(v);
            }
        }
    }
}

extern "C" void kernel_launch(void* const* d_in, const int* in_sizes, int n_in,
                              void* d_out, int out_size, void* d_ws, size_t ws_size,
                              hipStream_t stream) {
    const float* x = (const float*)d_in[0];   // [8][2][511][512] f32
    const float* w = (const float*)d_in[1];   // [2][257][511][511] f32
    u16* out = (u16*)d_out;                   // bf16, validated at +2 B
    float* A = (float*)d_ws;

    const size_t per_m = (size_t)NLAT * 32 * sizeof(float);   // 65,408 B
    int mchunk = (int)(ws_size / per_m);
    if (mchunk > MMAX) mchunk = MMAX;
    if (mchunk < 1) mchunk = 1;

    for (int m0 = 0; m0 < MMAX; m0 += mchunk) {
        int m1 = m0 + mchunk;
        if (m1 > MMAX) m1 = MMAX;
        const int mc = m1 - m0;
        fft3<<<NLAT * 2, 256, 0, stream>>>(x, A, m0, m1);
        legm<<<mc * 8, 256, 0, stream>>>(A, w, out, m0);
    }
}